// Round 1
// baseline (1873.948 us; speedup 1.0000x reference)
//
#include <hip/hip_runtime.h>
#include <cstdint>
#include <cstddef>

#define B_ 128
#define T_ 8192
#define F_ 10
#define F1_ 8
#define H1_ 8
#define H2_ 7
#define K_ 16
#define G1 (4*H1_)   // 32
#define G2 (4*H2_)   // 28

__device__ __forceinline__ float exp2_fast(float x){ float r; asm("v_exp_f32 %0, %1" : "=v"(r) : "v"(x)); return r; }
__device__ __forceinline__ float rcp_fast(float x){ float r; asm("v_rcp_f32 %0, %1" : "=v"(r) : "v"(x)); return r; }
__device__ __forceinline__ float tanh_fast(float x){
  // tanh(x) = 2/(1+exp2(-2*log2e*x)) - 1
  float e = exp2_fast(x * -2.8853900817779268f);
  return 2.f * rcp_fast(1.f + e) - 1.f;
}
__device__ __forceinline__ float rdlane(float v, int l){
  return __int_as_float(__builtin_amdgcn_readlane(__float_as_int(v), l));
}

// ---------------- Kernel 1: precompute LSTM1 gate inputs -------------------
__global__ __launch_bounds__(256) void k1_pre(const float* __restrict__ x,
    const float* __restrict__ conv_w, const float* __restrict__ conv_b,
    const float* __restrict__ w_ih1, const float* __restrict__ b_ih1,
    const float* __restrict__ b_hh1, float* __restrict__ g1pre)
{
  int idx = blockIdx.x*256 + threadIdx.x;   // (b*T + t)
  if (idx >= B_*T_) return;
  const float* xp = x + (size_t)idx*F_;
  float xv[F_];
  #pragma unroll
  for (int f=0; f<F_; ++f) xv[f] = xp[f];
  float enc[F1_];
  #pragma unroll
  for (int o=0;o<F1_;++o){
    float a = conv_b[o];
    #pragma unroll
    for (int f=0;f<F_;++f) a += conv_w[o*F_+f]*xv[f];
    enc[o] = a > 0.f ? a : 0.01f*a;   // leaky_relu 0.01
  }
  float* gp = g1pre + (size_t)idx*G1;
  #pragma unroll
  for (int g=0; g<G1; ++g){
    float a = b_ih1[g]+b_hh1[g];
    #pragma unroll
    for (int o=0;o<F1_;++o) a += w_ih1[g*F1_+o]*enc[o];
    gp[g] = a;
  }
}

// ---------------- Kernel 2: the two stacked LSTMs (recurrent) --------------
// One wave per batch element. Lane g<32: LSTM1 gate g (i:0-7,f:8-15,g:16-23,o:24-31)
// Lanes 32-63: LSTM2 gates padded to stride 8: cls=(lane-32)>>3, u=lane&7, row=cls*7+u (u<7).
// Pipelined: iteration n computes LSTM1 step n and LSTM2 step n-1.
__global__ __launch_bounds__(64,1) void k2_lstm(
    const float* __restrict__ g1pre,
    const float* __restrict__ w_hh1,
    const float* __restrict__ w_ih2, const float* __restrict__ w_hh2,
    const float* __restrict__ b_ih2, const float* __restrict__ b_hh2,
    float* __restrict__ zout)
{
  const int b = blockIdx.x;
  const int lane = threadIdx.x;
  const int cls = (lane>>3)&3;
  const int u = lane&7;

  float wA[8], wB[7], wC[8];
  float base2 = 0.f;
  #pragma unroll
  for (int j=0;j<8;++j){ wA[j]=0.f; wC[j]=0.f; }
  #pragma unroll
  for (int j=0;j<7;++j) wB[j]=0.f;
  if (lane < 32) {
    #pragma unroll
    for (int j=0;j<8;++j) wA[j] = w_hh1[lane*8+j];
  } else if (u < 7) {
    int row = cls*7 + u;
    #pragma unroll
    for (int j=0;j<7;++j) wB[j] = w_hh2[row*7+j];
    #pragma unroll
    for (int j=0;j<8;++j) wC[j] = w_ih2[row*8+j];
    base2 = b_ih2[row] + b_hh2[row];
  }
  const float LOG2E = 1.4426950408889634f;
  float A_, Sx_, D_;
  if (cls == 2) { A_=2.f; Sx_=-2.f*LOG2E; D_=-1.f; }   // tanh gate
  else          { A_=1.f; Sx_=-LOG2E;     D_=0.f;  }   // sigmoid gates

  float hq=0.f, cq=0.f;
  const float* wsb = g1pre + (size_t)b*T_*G1;
  float* zb = zout + (size_t)b*T_*H2_;
  const int lad = lane & 31;
  const bool isz = (lane>=32 && lane<32+H2_);

  float pf[8];
  #pragma unroll
  for (int up=0; up<8; ++up) pf[up] = wsb[(size_t)up*G1 + lad];

  auto step = [&](int n, float pre){
    float th_ = tanh_fast(hq);            // lanes0-7: tanh(h1[n-1]); lanes32-38: z[n-2]
    if (isz && n>=2) zb[(size_t)(n-2)*H2_ + (lane-32)] = th_;
    float sH1[8], sTh[8], sH2[7];
    #pragma unroll
    for (int j=0;j<8;++j) sH1[j] = rdlane(hq, j);
    #pragma unroll
    for (int j=0;j<8;++j) sTh[j] = rdlane(th_, j);
    #pragma unroll
    for (int j=0;j<7;++j) sH2[j] = rdlane(hq, 32+j);
    float a0=pre, a1=0.f, a2=0.f, a3=0.f;
    a0 += wA[0]*sH1[0]; a1 += wA[1]*sH1[1]; a2 += wA[2]*sH1[2]; a3 += wA[3]*sH1[3];
    a0 += wA[4]*sH1[4]; a1 += wA[5]*sH1[5]; a2 += wA[6]*sH1[6]; a3 += wA[7]*sH1[7];
    a0 += wC[0]*sTh[0]; a1 += wC[1]*sTh[1]; a2 += wC[2]*sTh[2]; a3 += wC[3]*sTh[3];
    a0 += wC[4]*sTh[4]; a1 += wC[5]*sTh[5]; a2 += wC[6]*sTh[6]; a3 += wC[7]*sTh[7];
    a0 += wB[0]*sH2[0]; a1 += wB[1]*sH2[1]; a2 += wB[2]*sH2[2]; a3 += wB[3]*sH2[3];
    a0 += wB[4]*sH2[4]; a1 += wB[5]*sH2[5]; a2 += wB[6]*sH2[6];
    float g = (a0+a1)+(a2+a3);
    float e = exp2_fast(Sx_*g);
    float y = A_*rcp_fast(1.f+e) + D_;    // per-lane sigmoid or tanh
    float yf = __shfl_xor(y, 8);
    float yg = __shfl_xor(y, 16);
    float yo = __shfl_xor(y, 24);
    float cn = yf*cq + y*yg;              // c' = sig(f)*c + sig(i)*tanh(g)  (valid in unit lanes)
    float tc = tanh_fast(cn);
    float hn = yo*tc;                     // h' = sig(o)*tanh(c')
    if (n==0 && lane>=32){ hn=0.f; cn=0.f; }  // LSTM2 "step -1" must not change state
    hq=hn; cq=cn;
  };

  for (int n0=0; n0<T_; n0+=8){
    #pragma unroll
    for (int up=0; up<8; ++up){
      int n = n0+up;
      float pre = (lane<32)? pf[up] : base2;
      int nn = n+8; if (nn > T_-1) nn = T_-1;
      pf[up] = wsb[(size_t)nn*G1 + lad];
      step(n, pre);
    }
  }
  // iteration n = T_: finishes LSTM2 step T-1, writes z[T-2]
  step(T_, (lane<32)? 0.f : base2);
  float thf = tanh_fast(hq);
  if (isz) zb[(size_t)(T_-1)*H2_ + (lane-32)] = thf;
}

// ---------------- Kernel 3: S[b,k] = sum_t Q[b,t,k] ------------------------
__global__ __launch_bounds__(256) void k3_S(const float* __restrict__ zout,
    const float* __restrict__ centers, float* __restrict__ S)
{
  int b = blockIdx.x; int tid = threadIdx.x;
  float cc[K_]; float cw[K_][H2_];
  #pragma unroll
  for (int k=0;k<K_;++k){ float s=0.f;
    #pragma unroll
    for (int j=0;j<H2_;++j){ float c=centers[k*H2_+j]; cw[k][j]=c; s+=c*c; }
    cc[k]=s; }
  float acc[K_];
  #pragma unroll
  for (int k=0;k<K_;++k) acc[k]=0.f;
  const float* zb = zout + (size_t)b*T_*H2_;
  for (int t=tid; t<T_; t+=256){
    float zv[H2_]; float zz=0.f;
    #pragma unroll
    for (int j=0;j<H2_;++j){ zv[j]=zb[(size_t)t*H2_+j]; zz+=zv[j]*zv[j]; }
    #pragma unroll
    for (int k=0;k<K_;++k){
      float d = zz + cc[k];
      #pragma unroll
      for (int j=0;j<H2_;++j) d -= 2.f*cw[k][j]*zv[j];
      acc[k] += rcp_fast(1.f + d);
    }
  }
  __shared__ float sred[4][K_];
  int wid = tid>>6;
  #pragma unroll
  for (int k=0;k<K_;++k){
    float v = acc[k];
    #pragma unroll
    for (int off=32; off; off>>=1) v += __shfl_down(v, off);
    acc[k]=v;
  }
  if ((tid&63)==0){
    #pragma unroll
    for (int k=0;k<K_;++k) sred[wid][k]=acc[k];
  }
  __syncthreads();
  if (tid < K_){
    S[b*K_+tid] = sred[0][tid]+sred[1][tid]+sred[2][tid]+sred[3][tid];
  }
}

// ---------------- Kernel 4: decoder + fq/fp --------------------------------
__global__ __launch_bounds__(256) void k4_out(const float* __restrict__ zout,
    const float* __restrict__ dec_w, const float* __restrict__ dec_b,
    const float* __restrict__ centers, const float* __restrict__ S,
    float* __restrict__ xr, float* __restrict__ fp, float* __restrict__ fq)
{
  int idx = blockIdx.x*256 + threadIdx.x;
  if (idx >= B_*T_) return;
  int b = idx >> 13;   // /T_
  float zv[H2_]; float zz=0.f;
  const float* zp = zout + (size_t)idx*H2_;
  #pragma unroll
  for (int j=0;j<H2_;++j){ zv[j]=zp[j]; zz+=zv[j]*zv[j]; }
  float* xp = xr + (size_t)idx*F_;
  #pragma unroll
  for (int f=0; f<F_; ++f){
    float a = dec_b[f];
    #pragma unroll
    for (int c=0;c<H2_;++c) a += zv[c]*dec_w[c*F_+f];
    xp[f]=a;
  }
  float Q[K_], P[K_]; float qs=0.f, ps=0.f;
  #pragma unroll
  for (int k=0;k<K_;++k){
    float d = zz;
    #pragma unroll
    for (int j=0;j<H2_;++j){ float c=centers[k*H2_+j]; d += c*c - 2.f*c*zv[j]; }
    float q = rcp_fast(1.f+d);
    Q[k]=q; qs+=q;
    float p = q*q*rcp_fast(S[b*K_+k]);
    P[k]=p; ps+=p;
  }
  float iq = rcp_fast(qs), ip = rcp_fast(ps);
  float* fqp = fq + (size_t)idx*K_;
  float* fpp = fp + (size_t)idx*K_;
  #pragma unroll
  for (int k=0;k<K_;++k){ fqp[k]=Q[k]*iq; fpp[k]=P[k]*ip; }
}

extern "C" void kernel_launch(void* const* d_in, const int* in_sizes, int n_in,
                              void* d_out, int out_size, void* d_ws, size_t ws_size,
                              hipStream_t stream)
{
  (void)in_sizes; (void)n_in; (void)out_size; (void)ws_size;
  const float* x      = (const float*)d_in[0];
  const float* conv_w = (const float*)d_in[1];
  const float* conv_b = (const float*)d_in[2];
  const float* w_ih1  = (const float*)d_in[3];
  const float* w_hh1  = (const float*)d_in[4];
  const float* b_ih1  = (const float*)d_in[5];
  const float* b_hh1  = (const float*)d_in[6];
  const float* w_ih2  = (const float*)d_in[7];
  const float* w_hh2  = (const float*)d_in[8];
  const float* b_ih2  = (const float*)d_in[9];
  const float* b_hh2  = (const float*)d_in[10];
  const float* dec_w  = (const float*)d_in[11];
  const float* dec_b  = (const float*)d_in[12];
  const float* centers= (const float*)d_in[13];

  float* out = (float*)d_out;
  float* z   = out;                              // [B,T,7]
  float* xr  = out + (size_t)B_*T_*H2_;          // [B,T,10]
  float* fp  = xr  + (size_t)B_*T_*F_;           // [B,T,16]
  float* fq  = fp  + (size_t)B_*T_*K_;           // [B,T,16]

  float* g1pre = (float*)d_ws;                   // 128 MB: [B,T,32]
  float* S     = (float*)d_ws;                   // reused after k2 (g1pre dead): [B,K]

  k1_pre<<<dim3((B_*T_)/256), dim3(256), 0, stream>>>(x, conv_w, conv_b, w_ih1, b_ih1, b_hh1, g1pre);
  k2_lstm<<<dim3(B_), dim3(64), 0, stream>>>(g1pre, w_hh1, w_ih2, w_hh2, b_ih2, b_hh2, z);
  k3_S<<<dim3(B_), dim3(256), 0, stream>>>(z, centers, S);
  k4_out<<<dim3((B_*T_)/256), dim3(256), 0, stream>>>(z, dec_w, dec_b, centers, S, xr, fp, fq);
}

// Round 2
// 1773.601 us; speedup vs baseline: 1.0566x; 1.0566x over previous
//
#include <hip/hip_runtime.h>
#include <cstdint>
#include <cstddef>

#define B_ 128
#define T_ 8192
#define F_ 10
#define F1_ 8
#define H1_ 8
#define H2_ 7
#define K_ 16

#define LOG2E 1.4426950408889634f

__device__ __forceinline__ float exp2_fast(float x){ float r; asm("v_exp_f32 %0, %1" : "=v"(r) : "v"(x)); return r; }
__device__ __forceinline__ float rcp_fast(float x){ float r; asm("v_rcp_f32 %0, %1" : "=v"(r) : "v"(x)); return r; }
__device__ __forceinline__ float rdlane(float v, int l){
  return __int_as_float(__builtin_amdgcn_readlane(__float_as_int(v), l));
}
// xor-8 within each 16-lane row (row_ror:8 == xor8 since 8 is half the row)
__device__ __forceinline__ float ror8(float x){
  return __int_as_float(__builtin_amdgcn_update_dpp(0, __float_as_int(x), 0x128, 0xF, 0xF, true));
}
typedef int v2i_t __attribute__((ext_vector_type(2)));
// lane i (i<32) receives y[i+32]; orientation-proof via exact bitwise xor3
__device__ __forceinline__ float swap32(float y){
  int yi = __float_as_int(y);
  v2i_t r = __builtin_amdgcn_permlane32_swap(yi, yi, false, false);
  return __int_as_float(r.x ^ r.y ^ yi);
}

// ---------------- Kernel 1: precompute LSTM1 gate inputs (pre-scaled) ------
// 8 lanes per timestep; each lane computes 4 gate rows -> one float4 store.
__global__ __launch_bounds__(256) void k1_pre(const float* __restrict__ x,
    const float* __restrict__ conv_w, const float* __restrict__ conv_b,
    const float* __restrict__ w_ih1, const float* __restrict__ b_ih1,
    const float* __restrict__ b_hh1, float* __restrict__ g1pre)
{
  int g8 = threadIdx.x >> 3;
  int gl = threadIdx.x & 7;
  size_t idx = (size_t)blockIdx.x*32 + g8;    // (b*T + t)
  const float* xp = x + idx*F_;
  float xv[F_];
  #pragma unroll
  for (int f=0; f<F_; ++f) xv[f] = xp[f];
  float enc[F1_];
  #pragma unroll
  for (int o=0;o<F1_;++o){
    float a = conv_b[o];
    #pragma unroll
    for (int f=0;f<F_;++f) a += conv_w[o*F_+f]*xv[f];
    enc[o] = a > 0.f ? a : 0.01f*a;   // leaky_relu 0.01
  }
  float4 out;
  #pragma unroll
  for (int q=0;q<4;++q){
    int row = gl*4+q;
    float a = b_ih1[row]+b_hh1[row];
    #pragma unroll
    for (int o=0;o<F1_;++o) a += w_ih1[row*F1_+o]*enc[o];
    float s = (row>=16 && row<24) ? (-2.f*LOG2E) : (-LOG2E);  // fold act scale
    (&out.x)[q] = a*s;
  }
  ((float4*)(g1pre + idx*32))[gl] = out;
}

// ---------------- Kernel 2: the two stacked LSTMs (recurrent) --------------
// Gate layout (unit u = lane&7):
//   lanes  0-15 : LSTM1 i(u) | f(u)       lanes 32-47 : LSTM1 g(u) | o(u)
//   lanes 16-31 : LSTM2 i(u) | f(u)       lanes 48-63 : LSTM2 g(u) | o(u)
// State: h1/c1 valid in lanes 0-7; h2/c2 valid in lanes 16-22.
// Gathers at unit lanes: f = ror8(y), g = swap32(y), o = ror8(swap32(y)).
// Pipelined: iteration n computes LSTM1 step n and LSTM2 step n-1.
__global__ __launch_bounds__(64,1) void k2_lstm(
    const float* __restrict__ g1pre,
    const float* __restrict__ w_hh1,
    const float* __restrict__ w_ih2, const float* __restrict__ w_hh2,
    const float* __restrict__ b_ih2, const float* __restrict__ b_hh2,
    float* __restrict__ zout)
{
  const int b = blockIdx.x;
  const int lane = threadIdx.x;
  const int u = lane & 7;
  const int half16 = (lane >> 3) & 1;
  const int upper  = lane >> 5;
  const int is2    = (lane >> 4) & 1;
  const int gi     = upper*2 + half16;       // 0=i,1=f,2=g,3=o

  const float Sx = (gi==2) ? (-2.f*LOG2E) : (-LOG2E);
  const float A_ = (gi==2) ? 2.f : 1.f;
  const float D_ = (gi==2) ? -1.f : 0.f;

  float wA[8], wB[7], wC[8]; float pre2 = 0.f;
  #pragma unroll
  for (int j=0;j<8;++j){ wA[j]=0.f; wC[j]=0.f; }
  #pragma unroll
  for (int j=0;j<7;++j) wB[j]=0.f;
  if (!is2){
    int row = gi*8+u;
    #pragma unroll
    for (int j=0;j<8;++j) wA[j] = w_hh1[row*8+j]*Sx;
  } else if (u < 7){
    int row = gi*7+u;
    #pragma unroll
    for (int j=0;j<8;++j) wC[j] = w_ih2[row*8+j]*Sx;
    #pragma unroll
    for (int j=0;j<7;++j) wB[j] = w_hh2[row*7+j]*Sx;
    pre2 = (b_ih2[row]+b_hh2[row])*Sx;
  }

  const int prow = gi*8+u;                       // g1pre row (LSTM1 lanes)
  const bool zlane = (is2 && upper==0 && half16==0 && u<7);  // lanes 16..22

  float hq=0.f, cq=0.f;
  const float* wsb = g1pre + (size_t)b*T_*32;
  float* zb = zout + (size_t)b*T_*H2_;

  float pf[8];
  #pragma unroll
  for (int up=0; up<8; ++up) pf[up] = wsb[(size_t)up*32 + prow];

  auto step = [&](int n, float pre){
    // th: lanes 0-7 = tanh(h1(n-1)) -> LSTM2 input; lanes 16-22 = z(n-2)
    float e0 = exp2_fast(hq * (-2.f*LOG2E));
    float th_ = 2.f*rcp_fast(1.f+e0) - 1.f;
    if (zlane && n>=2) zb[(size_t)(n-2)*H2_ + u] = th_;
    float sH1[8], sTh[8], sH2[7];
    #pragma unroll
    for (int j=0;j<8;++j) sH1[j] = rdlane(hq, j);
    #pragma unroll
    for (int j=0;j<8;++j) sTh[j] = rdlane(th_, j);
    #pragma unroll
    for (int j=0;j<7;++j) sH2[j] = rdlane(hq, 16+j);
    float a0=pre, a1=0.f, a2=0.f, a3=0.f;
    a0 += wA[0]*sH1[0]; a1 += wA[1]*sH1[1]; a2 += wA[2]*sH1[2]; a3 += wA[3]*sH1[3];
    a0 += wA[4]*sH1[4]; a1 += wA[5]*sH1[5]; a2 += wA[6]*sH1[6]; a3 += wA[7]*sH1[7];
    a0 += wB[0]*sH2[0]; a1 += wB[1]*sH2[1]; a2 += wB[2]*sH2[2]; a3 += wB[3]*sH2[3];
    a0 += wB[4]*sH2[4]; a1 += wB[5]*sH2[5]; a2 += wB[6]*sH2[6];
    a0 += wC[0]*sTh[0]; a1 += wC[1]*sTh[1]; a2 += wC[2]*sTh[2]; a3 += wC[3]*sTh[3];
    a0 += wC[4]*sTh[4]; a1 += wC[5]*sTh[5]; a2 += wC[6]*sTh[6]; a3 += wC[7]*sTh[7];
    float g = (a0+a1)+(a2+a3);                 // already scaled by Sx
    float e = exp2_fast(g);
    float y = fmaf(A_, rcp_fast(1.f+e), D_);   // sigmoid or tanh per lane
    float yf = ror8(y);
    float yg = swap32(y);
    float yo = ror8(yg);
    float cn = fmaf(yf, cq, y*yg);             // c' = sig(f)*c + sig(i)*tanh(g)
    float e2 = exp2_fast(cn * (-2.f*LOG2E));
    float tc = 2.f*rcp_fast(1.f+e2) - 1.f;
    float hn = yo*tc;                          // h' = sig(o)*tanh(c')
    if (n==0 && is2){ hn=0.f; cn=0.f; }        // LSTM2 "step -1" is a no-op
    hq=hn; cq=cn;
  };

  for (int n0=0; n0<T_; n0+=8){
    #pragma unroll
    for (int up=0; up<8; ++up){
      int n = n0+up;
      float pre = is2 ? pre2 : pf[up];
      int nn = n+8; if (nn > T_-1) nn = T_-1;
      pf[up] = wsb[(size_t)nn*32 + prow];
      step(n, pre);
    }
  }
  step(T_, is2 ? pre2 : 0.f);                  // finishes LSTM2 step T-1
  float e0 = exp2_fast(hq * (-2.f*LOG2E));
  float thf = 2.f*rcp_fast(1.f+e0) - 1.f;
  if (zlane) zb[(size_t)(T_-1)*H2_ + u] = thf;
}

// ---------------- Kernel 3: S[b,k] = sum_t Q[b,t,k] ------------------------
__global__ __launch_bounds__(256) void k3_S(const float* __restrict__ zout,
    const float* __restrict__ centers, float* __restrict__ S)
{
  int b = blockIdx.x; int tid = threadIdx.x;
  float cc[K_]; float cw[K_][H2_];
  #pragma unroll
  for (int k=0;k<K_;++k){ float s=0.f;
    #pragma unroll
    for (int j=0;j<H2_;++j){ float c=centers[k*H2_+j]; cw[k][j]=c; s+=c*c; }
    cc[k]=s; }
  float acc[K_];
  #pragma unroll
  for (int k=0;k<K_;++k) acc[k]=0.f;
  const float* zb = zout + (size_t)b*T_*H2_;
  for (int t=tid; t<T_; t+=256){
    float zv[H2_]; float zz=0.f;
    #pragma unroll
    for (int j=0;j<H2_;++j){ zv[j]=zb[(size_t)t*H2_+j]; zz+=zv[j]*zv[j]; }
    #pragma unroll
    for (int k=0;k<K_;++k){
      float d = zz + cc[k];
      #pragma unroll
      for (int j=0;j<H2_;++j) d -= 2.f*cw[k][j]*zv[j];
      acc[k] += rcp_fast(1.f + d);
    }
  }
  __shared__ float sred[4][K_];
  int wid = tid>>6;
  #pragma unroll
  for (int k=0;k<K_;++k){
    float v = acc[k];
    #pragma unroll
    for (int off=32; off; off>>=1) v += __shfl_down(v, off);
    acc[k]=v;
  }
  if ((tid&63)==0){
    #pragma unroll
    for (int k=0;k<K_;++k) sred[wid][k]=acc[k];
  }
  __syncthreads();
  if (tid < K_){
    S[b*K_+tid] = sred[0][tid]+sred[1][tid]+sred[2][tid]+sred[3][tid];
  }
}

// ---------------- Kernel 4: decoder + fq/fp --------------------------------
__global__ __launch_bounds__(256) void k4_out(const float* __restrict__ zout,
    const float* __restrict__ dec_w, const float* __restrict__ dec_b,
    const float* __restrict__ centers, const float* __restrict__ S,
    float* __restrict__ xr, float* __restrict__ fp, float* __restrict__ fq)
{
  int idx = blockIdx.x*256 + threadIdx.x;
  if (idx >= B_*T_) return;
  int b = idx >> 13;   // /T_
  float zv[H2_]; float zz=0.f;
  const float* zp = zout + (size_t)idx*H2_;
  #pragma unroll
  for (int j=0;j<H2_;++j){ zv[j]=zp[j]; zz+=zv[j]*zv[j]; }
  // decoder: 10 floats, idx*40B is 8B-aligned -> float2 x5
  float2 xo[5];
  #pragma unroll
  for (int f=0; f<F_; ++f){
    float a = dec_b[f];
    #pragma unroll
    for (int c=0;c<H2_;++c) a += zv[c]*dec_w[c*F_+f];
    (&xo[0].x)[f] = a;
  }
  float2* xp2 = (float2*)(xr + (size_t)idx*F_);
  #pragma unroll
  for (int c=0;c<5;++c) xp2[c] = xo[c];

  float Q[K_], P[K_]; float qs=0.f, ps=0.f;
  #pragma unroll
  for (int k=0;k<K_;++k){
    float d = zz;
    #pragma unroll
    for (int j=0;j<H2_;++j){ float c=centers[k*H2_+j]; d += c*c - 2.f*c*zv[j]; }
    float q = rcp_fast(1.f+d);
    Q[k]=q; qs+=q;
    float p = q*q*rcp_fast(S[b*K_+k]);
    P[k]=p; ps+=p;
  }
  float iq = rcp_fast(qs), ip = rcp_fast(ps);
  float4* fqp = (float4*)(fq + (size_t)idx*K_);
  float4* fpp = (float4*)(fp + (size_t)idx*K_);
  #pragma unroll
  for (int c=0;c<4;++c){
    float4 vq, vp;
    vq.x=Q[4*c+0]*iq; vq.y=Q[4*c+1]*iq; vq.z=Q[4*c+2]*iq; vq.w=Q[4*c+3]*iq;
    vp.x=P[4*c+0]*ip; vp.y=P[4*c+1]*ip; vp.z=P[4*c+2]*ip; vp.w=P[4*c+3]*ip;
    fqp[c]=vq; fpp[c]=vp;
  }
}

extern "C" void kernel_launch(void* const* d_in, const int* in_sizes, int n_in,
                              void* d_out, int out_size, void* d_ws, size_t ws_size,
                              hipStream_t stream)
{
  (void)in_sizes; (void)n_in; (void)out_size; (void)ws_size;
  const float* x      = (const float*)d_in[0];
  const float* conv_w = (const float*)d_in[1];
  const float* conv_b = (const float*)d_in[2];
  const float* w_ih1  = (const float*)d_in[3];
  const float* w_hh1  = (const float*)d_in[4];
  const float* b_ih1  = (const float*)d_in[5];
  const float* b_hh1  = (const float*)d_in[6];
  const float* w_ih2  = (const float*)d_in[7];
  const float* w_hh2  = (const float*)d_in[8];
  const float* b_ih2  = (const float*)d_in[9];
  const float* b_hh2  = (const float*)d_in[10];
  const float* dec_w  = (const float*)d_in[11];
  const float* dec_b  = (const float*)d_in[12];
  const float* centers= (const float*)d_in[13];

  float* out = (float*)d_out;
  float* z   = out;                              // [B,T,7]
  float* xr  = out + (size_t)B_*T_*H2_;          // [B,T,10]
  float* fp  = xr  + (size_t)B_*T_*F_;           // [B,T,16]
  float* fq  = fp  + (size_t)B_*T_*K_;           // [B,T,16]

  float* g1pre = (float*)d_ws;                   // 128 MB: [B,T,32] (pre-scaled)
  float* S     = (float*)d_ws;                   // reused after k2: [B,K]

  k1_pre<<<dim3((B_*T_)/32), dim3(256), 0, stream>>>(x, conv_w, conv_b, w_ih1, b_ih1, b_hh1, g1pre);
  k2_lstm<<<dim3(B_), dim3(64), 0, stream>>>(g1pre, w_hh1, w_ih2, w_hh2, b_ih2, b_hh2, z);
  k3_S<<<dim3(B_), dim3(256), 0, stream>>>(z, centers, S);
  k4_out<<<dim3((B_*T_)/256), dim3(256), 0, stream>>>(z, dec_w, dec_b, centers, S, xr, fp, fq);
}

// Round 3
// 1490.594 us; speedup vs baseline: 1.2572x; 1.1899x over previous
//
#include <hip/hip_runtime.h>
#include <cstdint>
#include <cstddef>

#define B_ 128
#define T_ 8192
#define F_ 10
#define F1_ 8
#define H1_ 8
#define H2_ 7
#define K_ 16
#define CHUNK 64
#define NC (T_/CHUNK)   // 128

#define LOG2E 1.4426950408889634f

__device__ __forceinline__ float exp2_fast(float x){ float r; asm("v_exp_f32 %0, %1" : "=v"(r) : "v"(x)); return r; }
__device__ __forceinline__ float rcp_fast(float x){ float r; asm("v_rcp_f32 %0, %1" : "=v"(r) : "v"(x)); return r; }
__device__ __forceinline__ float tanh2(float x){
  float e = exp2_fast(x * (-2.f*LOG2E));
  return fmaf(2.f, rcp_fast(1.f + e), -1.f);
}
__device__ __forceinline__ float rdlane(float v, int l){
  return __int_as_float(__builtin_amdgcn_readlane(__float_as_int(v), l));
}
// xor-8 within each 16-lane row (row_ror:8)
__device__ __forceinline__ float ror8(float x){
  return __int_as_float(__builtin_amdgcn_update_dpp(0, __float_as_int(x), 0x128, 0xF, 0xF, true));
}
typedef int v2i_t __attribute__((ext_vector_type(2)));
// lane i receives value from lane i^32; orientation-proof via bitwise xor3
__device__ __forceinline__ float swap32(float y){
  int yi = __float_as_int(y);
  v2i_t r = __builtin_amdgcn_permlane32_swap(yi, yi, false, false);
  return __int_as_float(r.x ^ r.y ^ yi);
}

// ---------------- Kernel 1: precompute LSTM1 gate inputs (pre-scaled) ------
__global__ __launch_bounds__(256) void k1_pre(const float* __restrict__ x,
    const float* __restrict__ conv_w, const float* __restrict__ conv_b,
    const float* __restrict__ w_ih1, const float* __restrict__ b_ih1,
    const float* __restrict__ b_hh1, float* __restrict__ g1pre)
{
  int g8 = threadIdx.x >> 3;
  int gl = threadIdx.x & 7;
  size_t idx = (size_t)blockIdx.x*32 + g8;    // (b*T + t)
  const float* xp = x + idx*F_;
  float xv[F_];
  #pragma unroll
  for (int f=0; f<F_; ++f) xv[f] = xp[f];
  float enc[F1_];
  #pragma unroll
  for (int o=0;o<F1_;++o){
    float a = conv_b[o];
    #pragma unroll
    for (int f=0;f<F_;++f) a += conv_w[o*F_+f]*xv[f];
    enc[o] = a > 0.f ? a : 0.01f*a;   // leaky_relu 0.01
  }
  float4 out;
  #pragma unroll
  for (int q=0;q<4;++q){
    int row = gl*4+q;
    float a = b_ih1[row]+b_hh1[row];
    #pragma unroll
    for (int o=0;o<F1_;++o) a += w_ih1[row*F1_+o]*enc[o];
    float s = (row>=16 && row<24) ? (-2.f*LOG2E) : (-LOG2E);  // fold act scale
    (&out.x)[q] = a*s;
  }
  ((float4*)(g1pre + idx*32))[gl] = out;
}

// ---------------- Kernel 2: wave-specialized stacked LSTMs -----------------
// Block = 128 threads = 2 waves. Wave 0: LSTM1 (producer). Wave 1: LSTM2
// (consumer). tanh(h1) streams through a 3-slot LDS ring of 64-step chunks.
// Gate lane layout (both waves): i: lanes 0-7, f: 8-15, g: 32-39, o: 40-47
// (lanes 16-31/48-63 duplicate rows 0-15/16-31 — results unused).
// Gathers to unit lanes 0-7: f=ror8(y), g=swap32(y), o=ror8(swap32(y)).
__global__ __launch_bounds__(128,1) void k2_lstm(
    const float* __restrict__ g1pre,
    const float* __restrict__ w_hh1,
    const float* __restrict__ w_ih2, const float* __restrict__ w_hh2,
    const float* __restrict__ b_ih2, const float* __restrict__ b_hh2,
    float* __restrict__ zout)
{
  __shared__ float th_buf[3][CHUNK][8];   // 6 KB ring
  const int b = blockIdx.x;
  const int wv = threadIdx.x >> 6;
  const int lane = threadIdx.x & 63;
  const int u = lane & 7;
  const int row = (lane & 15) + ((lane >> 5) << 4);   // 0..31 (dup on idle quarters)
  const int gi = row >> 3;                            // 0=i,1=f,2=g,3=o

  const float Sx = (gi==2) ? (-2.f*LOG2E) : (-LOG2E);
  const float A_ = (gi==2) ? 2.f : 1.f;
  const float D_ = (gi==2) ? -1.f : 0.f;

  if (wv == 0) {
    // ---------------- Wave A: LSTM1 ----------------
    float wA[8];
    #pragma unroll
    for (int j=0;j<8;++j) wA[j] = w_hh1[row*8+j]*Sx;
    const float* wsb = g1pre + (size_t)b*T_*32 + row;
    float hq=0.f, cq=0.f;
    float pf[8];
    #pragma unroll
    for (int up=0; up<8; ++up) pf[up] = wsb[(size_t)up*32];
    const bool wr = (lane < 8);

    for (int c=0; c<NC; ++c){
      if (c >= 2) { asm volatile("s_waitcnt lgkmcnt(0)\n\ts_barrier" ::: "memory"); }
      float* tb = &th_buf[c%3][0][0];
      for (int t0=0; t0<CHUNK; t0+=8){
        #pragma unroll
        for (int up=0; up<8; ++up){
          int t = c*CHUNK + t0 + up;
          float pre = pf[up];
          int nn = t+8; if (nn > T_-1) nn = T_-1;
          pf[up] = wsb[(size_t)nn*32];
          float s0=rdlane(hq,0), s1=rdlane(hq,1), s2=rdlane(hq,2), s3=rdlane(hq,3);
          float s4=rdlane(hq,4), s5=rdlane(hq,5), s6=rdlane(hq,6), s7=rdlane(hq,7);
          float a0 = fmaf(wA[0],s0,pre);
          float a1 = wA[1]*s1, a2 = wA[2]*s2, a3 = wA[3]*s3;
          a0 = fmaf(wA[4],s4,a0); a1 = fmaf(wA[5],s5,a1);
          a2 = fmaf(wA[6],s6,a2); a3 = fmaf(wA[7],s7,a3);
          float g = (a0+a1)+(a2+a3);
          float e = exp2_fast(g);
          float y = fmaf(A_, rcp_fast(1.f+e), D_);
          float yf = ror8(y);
          float yg = swap32(y);
          float yo = ror8(yg);
          float cn = fmaf(yf, cq, y*yg);
          float tc = tanh2(cn);
          float hn = yo*tc;
          hq = hn; cq = cn;
          float th = tanh2(hn);
          if (wr) tb[(t0+up)*8 + u] = th;
        }
      }
    }
    asm volatile("s_waitcnt lgkmcnt(0)\n\ts_barrier" ::: "memory");
    asm volatile("s_barrier" ::: "memory");
  } else {
    // ---------------- Wave B: LSTM2 ----------------
    float wC[8], wB[7]; float pre2 = 0.f;
    #pragma unroll
    for (int j=0;j<8;++j) wC[j]=0.f;
    #pragma unroll
    for (int j=0;j<7;++j) wB[j]=0.f;
    if (u < 7){
      int r2 = gi*7 + u;
      #pragma unroll
      for (int j=0;j<8;++j) wC[j] = w_ih2[r2*8+j]*Sx;
      #pragma unroll
      for (int j=0;j<7;++j) wB[j] = w_hh2[r2*7+j]*Sx;
      pre2 = (b_ih2[r2]+b_hh2[r2])*Sx;
    }
    float hq=0.f, cq=0.f;
    float* zb = zout + (size_t)b*T_*H2_;
    const bool zw = (lane < 7);

    asm volatile("s_barrier" ::: "memory");   // BAR #1: chunks 0,1 ready
    // prologue prefetch t=0,1
    float4 thL[2], thH[2];
    {
      const float4* p0 = (const float4*)&th_buf[0][0][0];
      thL[0] = p0[0]; thH[0] = p0[1];
      const float4* p1 = (const float4*)&th_buf[0][1][0];
      thL[1] = p1[0]; thH[1] = p1[1];
    }
    for (int c=0; c<NC; ++c){
      if (c > 0) { asm volatile("s_barrier" ::: "memory"); }
      for (int t0=0; t0<CHUNK; t0+=8){
        #pragma unroll
        for (int up=0; up<8; ++up){
          int t = c*CHUNK + t0 + up;
          const int p = up & 1;
          float4 lo = thL[p], hi = thH[p];
          int tp = t + 2;                      // prefetch 2 steps ahead
          int slot = (tp >> 6) % 3;
          const float4* pa = (const float4*)&th_buf[slot][tp & (CHUNK-1)][0];
          thL[p] = pa[0]; thH[p] = pa[1];
          float s0=rdlane(hq,0), s1=rdlane(hq,1), s2=rdlane(hq,2), s3=rdlane(hq,3);
          float s4=rdlane(hq,4), s5=rdlane(hq,5), s6=rdlane(hq,6);
          // input-projection part (off the recurrence chain)
          float a0 = fmaf(wC[0], lo.x, pre2);
          float a1 = wC[1]*lo.y, a2 = wC[2]*lo.z, a3 = wC[3]*lo.w;
          float a4 = wC[4]*hi.x, a5 = wC[5]*hi.y, a6 = wC[6]*hi.z, a7 = wC[7]*hi.w;
          // recurrent part: depth-1 FMA per accumulator
          a0 = fmaf(wB[0],s0,a0); a1 = fmaf(wB[1],s1,a1);
          a2 = fmaf(wB[2],s2,a2); a3 = fmaf(wB[3],s3,a3);
          a4 = fmaf(wB[4],s4,a4); a5 = fmaf(wB[5],s5,a5);
          a6 = fmaf(wB[6],s6,a6);
          float g = ((a0+a1)+(a2+a3)) + ((a4+a5)+(a6+a7));
          float e = exp2_fast(g);
          float y = fmaf(A_, rcp_fast(1.f+e), D_);
          float yf = ror8(y);
          float yg = swap32(y);
          float yo = ror8(yg);
          float cn = fmaf(yf, cq, y*yg);
          float tc = tanh2(cn);
          float hn = yo*tc;
          hq = hn; cq = cn;
          float z = tanh2(hn);
          if (zw) zb[(size_t)t*H2_ + lane] = z;
        }
      }
    }
  }
}

// ---------------- Kernel 3: S[b,k] = sum_t Q[b,t,k] ------------------------
__global__ __launch_bounds__(256) void k3_S(const float* __restrict__ zout,
    const float* __restrict__ centers, float* __restrict__ S)
{
  int b = blockIdx.x; int tid = threadIdx.x;
  float cc[K_]; float cw[K_][H2_];
  #pragma unroll
  for (int k=0;k<K_;++k){ float s=0.f;
    #pragma unroll
    for (int j=0;j<H2_;++j){ float c=centers[k*H2_+j]; cw[k][j]=c; s+=c*c; }
    cc[k]=s; }
  float acc[K_];
  #pragma unroll
  for (int k=0;k<K_;++k) acc[k]=0.f;
  const float* zb = zout + (size_t)b*T_*H2_;
  for (int t=tid; t<T_; t+=256){
    float zv[H2_]; float zz=0.f;
    #pragma unroll
    for (int j=0;j<H2_;++j){ zv[j]=zb[(size_t)t*H2_+j]; zz+=zv[j]*zv[j]; }
    #pragma unroll
    for (int k=0;k<K_;++k){
      float d = zz + cc[k];
      #pragma unroll
      for (int j=0;j<H2_;++j) d -= 2.f*cw[k][j]*zv[j];
      acc[k] += rcp_fast(1.f + d);
    }
  }
  __shared__ float sred[4][K_];
  int wid = tid>>6;
  #pragma unroll
  for (int k=0;k<K_;++k){
    float v = acc[k];
    #pragma unroll
    for (int off=32; off; off>>=1) v += __shfl_down(v, off);
    acc[k]=v;
  }
  if ((tid&63)==0){
    #pragma unroll
    for (int k=0;k<K_;++k) sred[wid][k]=acc[k];
  }
  __syncthreads();
  if (tid < K_){
    S[b*K_+tid] = sred[0][tid]+sred[1][tid]+sred[2][tid]+sred[3][tid];
  }
}

// ---------------- Kernel 4: decoder + fq/fp --------------------------------
__global__ __launch_bounds__(256) void k4_out(const float* __restrict__ zout,
    const float* __restrict__ dec_w, const float* __restrict__ dec_b,
    const float* __restrict__ centers, const float* __restrict__ S,
    float* __restrict__ xr, float* __restrict__ fp, float* __restrict__ fq)
{
  int idx = blockIdx.x*256 + threadIdx.x;
  if (idx >= B_*T_) return;
  int b = idx >> 13;   // /T_
  float zv[H2_]; float zz=0.f;
  const float* zp = zout + (size_t)idx*H2_;
  #pragma unroll
  for (int j=0;j<H2_;++j){ zv[j]=zp[j]; zz+=zv[j]*zv[j]; }
  float2 xo[5];
  #pragma unroll
  for (int f=0; f<F_; ++f){
    float a = dec_b[f];
    #pragma unroll
    for (int c=0;c<H2_;++c) a += zv[c]*dec_w[c*F_+f];
    (&xo[0].x)[f] = a;
  }
  float2* xp2 = (float2*)(xr + (size_t)idx*F_);
  #pragma unroll
  for (int c=0;c<5;++c) xp2[c] = xo[c];

  float Q[K_], P[K_]; float qs=0.f, ps=0.f;
  #pragma unroll
  for (int k=0;k<K_;++k){
    float d = zz;
    #pragma unroll
    for (int j=0;j<H2_;++j){ float c=centers[k*H2_+j]; d += c*c - 2.f*c*zv[j]; }
    float q = rcp_fast(1.f+d);
    Q[k]=q; qs+=q;
    float p = q*q*rcp_fast(S[b*K_+k]);
    P[k]=p; ps+=p;
  }
  float iq = rcp_fast(qs), ip = rcp_fast(ps);
  float4* fqp = (float4*)(fq + (size_t)idx*K_);
  float4* fpp = (float4*)(fp + (size_t)idx*K_);
  #pragma unroll
  for (int c=0;c<4;++c){
    float4 vq, vp;
    vq.x=Q[4*c+0]*iq; vq.y=Q[4*c+1]*iq; vq.z=Q[4*c+2]*iq; vq.w=Q[4*c+3]*iq;
    vp.x=P[4*c+0]*ip; vp.y=P[4*c+1]*ip; vp.z=P[4*c+2]*ip; vp.w=P[4*c+3]*ip;
    fqp[c]=vq; fpp[c]=vp;
  }
}

extern "C" void kernel_launch(void* const* d_in, const int* in_sizes, int n_in,
                              void* d_out, int out_size, void* d_ws, size_t ws_size,
                              hipStream_t stream)
{
  (void)in_sizes; (void)n_in; (void)out_size; (void)ws_size;
  const float* x      = (const float*)d_in[0];
  const float* conv_w = (const float*)d_in[1];
  const float* conv_b = (const float*)d_in[2];
  const float* w_ih1  = (const float*)d_in[3];
  const float* w_hh1  = (const float*)d_in[4];
  const float* b_ih1  = (const float*)d_in[5];
  const float* b_hh1  = (const float*)d_in[6];
  const float* w_ih2  = (const float*)d_in[7];
  const float* w_hh2  = (const float*)d_in[8];
  const float* b_ih2  = (const float*)d_in[9];
  const float* b_hh2  = (const float*)d_in[10];
  const float* dec_w  = (const float*)d_in[11];
  const float* dec_b  = (const float*)d_in[12];
  const float* centers= (const float*)d_in[13];

  float* out = (float*)d_out;
  float* z   = out;                              // [B,T,7]
  float* xr  = out + (size_t)B_*T_*H2_;          // [B,T,10]
  float* fp  = xr  + (size_t)B_*T_*F_;           // [B,T,16]
  float* fq  = fp  + (size_t)B_*T_*K_;           // [B,T,16]

  float* g1pre = (float*)d_ws;                   // 128 MB: [B,T,32] (pre-scaled)
  float* S     = (float*)d_ws;                   // reused after k2: [B,K]

  k1_pre<<<dim3((B_*T_)/32), dim3(256), 0, stream>>>(x, conv_w, conv_b, w_ih1, b_ih1, b_hh1, g1pre);
  k2_lstm<<<dim3(B_), dim3(128), 0, stream>>>(g1pre, w_hh1, w_ih2, w_hh2, b_ih2, b_hh2, z);
  k3_S<<<dim3(B_), dim3(256), 0, stream>>>(z, centers, S);
  k4_out<<<dim3((B_*T_)/256), dim3(256), 0, stream>>>(z, dec_w, dec_b, centers, S, xr, fp, fq);
}